// Round 12
// baseline (139.389 us; speedup 1.0000x reference)
//
#include <hip/hip_runtime.h>
#include <math.h>

typedef short bf16x8 __attribute__((ext_vector_type(8)));
typedef float f32x4 __attribute__((ext_vector_type(4)));
typedef float f32x16 __attribute__((ext_vector_type(16)));
typedef int int2v __attribute__((ext_vector_type(2)));

constexpr int Bc = 2, Tc = 2048, Cc = 1024, Hc = 16, Dc = 64;
constexpr int Mc = Bc * Tc;  // 4096

#if __has_builtin(__builtin_amdgcn_exp2f)
#define EXP2(x) __builtin_amdgcn_exp2f(x)
#else
#define EXP2(x) exp2f(x)
#endif

#define SBAR() do { asm volatile("" ::: "memory"); \
                    __builtin_amdgcn_s_barrier();   \
                    asm volatile("" ::: "memory"); } while (0)

__device__ __forceinline__ unsigned short f2bf(float f) {
    union { float f; unsigned u; } v; v.f = f;
    unsigned r = v.u + 0x7fffu + ((v.u >> 16) & 1u);  // RNE
    return (unsigned short)(r >> 16);
}

__device__ __forceinline__ float bf2f(unsigned short u) {
    union { unsigned u; float f; } v; v.u = (unsigned)u << 16; return v.f;
}

__device__ __forceinline__ unsigned cvt_pk_bf16(float lo, float hi) {
    unsigned r;
    asm("v_cvt_pk_bf16_f32 %0, %1, %2" : "=v"(r) : "v"(lo), "v"(hi));
    return r;
}

__device__ __forceinline__ void gload16(const void* g, void* l) {
    __builtin_amdgcn_global_load_lds(
        (const __attribute__((address_space(1))) void*)g,
        (__attribute__((address_space(3))) void*)l, 16, 0, 0);
}

// ---------------------------------------------------------------------------
__global__ __launch_bounds__(256)
void cast_bf16(const float* __restrict__ in, unsigned short* __restrict__ out, int n8) {
    int i = blockIdx.x * 256 + threadIdx.x;
    if (i >= n8) return;
    const float4* p = (const float4*)in;
    float4 a = p[i * 2], b = p[i * 2 + 1];
    union { unsigned short u[8]; bf16x8 v; } r;
    r.u[0] = f2bf(a.x); r.u[1] = f2bf(a.y); r.u[2] = f2bf(a.z); r.u[3] = f2bf(a.w);
    r.u[4] = f2bf(b.x); r.u[5] = f2bf(b.y); r.u[6] = f2bf(b.z); r.u[7] = f2bf(b.w);
    *(bf16x8*)(out + i * 8) = r.v;
}

__global__ __launch_bounds__(256)
void cast_w4(const float* __restrict__ a, const float* __restrict__ b,
             const float* __restrict__ c, const float* __restrict__ d,
             unsigned short* __restrict__ oa, unsigned short* __restrict__ ob,
             unsigned short* __restrict__ oc, unsigned short* __restrict__ od) {
    const float* src = blockIdx.y == 0 ? a : blockIdx.y == 1 ? b : blockIdx.y == 2 ? c : d;
    unsigned short* dst = blockIdx.y == 0 ? oa : blockIdx.y == 1 ? ob : blockIdx.y == 2 ? oc : od;
    int i = blockIdx.x * 256 + threadIdx.x;
    const float4* p = (const float4*)src;
    float4 x = p[i * 2], y = p[i * 2 + 1];
    union { unsigned short u[8]; bf16x8 v; } r;
    r.u[0] = f2bf(x.x); r.u[1] = f2bf(x.y); r.u[2] = f2bf(x.z); r.u[3] = f2bf(x.w);
    r.u[4] = f2bf(y.x); r.u[5] = f2bf(y.y); r.u[6] = f2bf(y.z); r.u[7] = f2bf(y.w);
    *(bf16x8*)(dst + i * 8) = r.v;
}

// ---------------------------------------------------------------------------
// Fused QKV GEMM (NT): 256x256 tile, BK=32, 8 waves (2Mx4N), double-buffered
// LDS (2 slots, 64 KB), counted vmcnt(4) -- next K-tile's loads stay in
// flight across barriers; stage for kt+2 issued AFTER compute of kt (slot
// freed a full group earlier -> latency fully hidden). T2 chunk-XOR swizzle
// (pre-swizzled source + swizzled reads, rule 21). Grid 16x12 = 192 blocks.
// blockIdx.y: seg = y>>2 (0=Q scaled, 1=K, 2=V^T), n0 = (y&3)*256.
// ---------------------------------------------------------------------------
__global__ __launch_bounds__(512)
void gemm_qkv(const unsigned short* __restrict__ A,
              const unsigned short* __restrict__ Wq,
              const unsigned short* __restrict__ Wk,
              const unsigned short* __restrict__ Wv,
              unsigned short* __restrict__ Qo,
              unsigned short* __restrict__ Ko,
              unsigned short* __restrict__ Vo) {
    __shared__ unsigned short As[2][256 * 32];   // 32 KB
    __shared__ unsigned short Bs[2][256 * 32];   // 32 KB
    const int t = threadIdx.x;                   // 0..511
    const int lane = t & 63, l15 = lane & 15, l4 = lane >> 4;
    const int w = t >> 6;                        // 0..7
    const int wm = w >> 2, wn = w & 3;           // 2 x 4 wave grid
    const int seg = blockIdx.y >> 2;
    const unsigned short* W = seg == 0 ? Wq : seg == 1 ? Wk : Wv;
    const int m0 = blockIdx.x * 256, n0 = (blockIdx.y & 3) * 256;

    f32x4 acc[8][4] = {};

    // stage one K-tile (A 256x32 + B 256x32), 4 gload16/thread.
    // chunk swizzle: ss = sl ^ ((row>>1)&3)  (involution, 2-way-free reads)
    auto stageKT = [&](int kt) {
        const int s = kt & 1;
        #pragma unroll
        for (int it = 0; it < 2; ++it) {
            int idx = t + it * 512;               // 0..1023
            int row = idx >> 2, sl = idx & 3;
            int ss = sl ^ ((row >> 1) & 3);
            gload16(A + (size_t)(m0 + row) * Cc + kt * 32 + ss * 8, &As[s][idx * 8]);
            gload16(W + (size_t)(n0 + row) * Cc + kt * 32 + ss * 8, &Bs[s][idx * 8]);
        }
    };

    stageKT(0);
    stageKT(1);

    const int NKT = Cc / 32;    // 32
    for (int kt = 0; kt < NKT; ++kt) {
        const int s = kt & 1;
        // kt's 4 loads landed; kt+1's 4 stay in flight
        if (kt + 1 < NKT) asm volatile("s_waitcnt vmcnt(4)" ::: "memory");
        else              asm volatile("s_waitcnt vmcnt(0)" ::: "memory");
        SBAR();

        bf16x8 af[8], bf[4];
        #pragma unroll
        for (int ii = 0; ii < 8; ++ii) {
            int row = wm * 128 + ii * 16 + l15;
            int ch = l4 ^ ((row >> 1) & 3);
            af[ii] = *(const bf16x8*)(&As[s][row * 32 + ch * 8]);
        }
        #pragma unroll
        for (int jj = 0; jj < 4; ++jj) {
            int row = wn * 64 + jj * 16 + l15;
            int ch = l4 ^ ((row >> 1) & 3);
            bf[jj] = *(const bf16x8*)(&Bs[s][row * 32 + ch * 8]);
        }
        __builtin_amdgcn_s_setprio(1);
        #pragma unroll
        for (int ii = 0; ii < 8; ++ii)
            #pragma unroll
            for (int jj = 0; jj < 4; ++jj)
                acc[ii][jj] = __builtin_amdgcn_mfma_f32_16x16x32_bf16(af[ii], bf[jj], acc[ii][jj], 0, 0, 0);
        __builtin_amdgcn_s_setprio(0);

        SBAR();                      // all waves done reading slot s
        if (kt + 2 < NKT) stageKT(kt + 2);
    }

    const float qscale = 0.18033688011112042f;  // 0.125 * log2(e)
    #pragma unroll
    for (int ii = 0; ii < 8; ++ii)
        #pragma unroll
        for (int jj = 0; jj < 4; ++jj)
            #pragma unroll
            for (int r = 0; r < 4; ++r) {
                int row = m0 + wm * 128 + ii * 16 + (l4 << 2) + r;
                int col = n0 + wn * 64 + jj * 16 + l15;
                float v = acc[ii][jj][r];
                int bb = row >> 11, tt = row & (Tc - 1);
                int hh = col >> 6, dd = col & 63;
                if (seg == 0)
                    Qo[((((size_t)bb * Hc + hh) * Tc + tt) << 6) + dd] = f2bf(v * qscale);
                else if (seg == 1)
                    Ko[((((size_t)bb * Hc + hh) * Tc + tt) << 6) + dd] = f2bf(v);
                else
                    Vo[(((size_t)bb * Hc + hh) * Dc + dd) * Tc + tt] = f2bf(v);
            }
}

// ---------------------------------------------------------------------------
// Out-projection GEMM (NT): 64x64 tile, 1024 blocks (4/CU), fp32 out [M,C].
// ---------------------------------------------------------------------------
__global__ __launch_bounds__(256)
void gemm_out(const unsigned short* __restrict__ A,
              const unsigned short* __restrict__ W,
              float* __restrict__ outp) {
    __shared__ unsigned short As[64 * 32];
    __shared__ unsigned short Bs[64 * 32];
    const int t = threadIdx.x;
    const int lane = t & 63, l15 = lane & 15, l4 = lane >> 4;
    const int w = t >> 6, wr = w >> 1, wc = w & 1;
    const int m0 = blockIdx.x * 64, n0 = blockIdx.y * 64;

    f32x4 acc[2][2] = {};

    for (int k0 = 0; k0 < Cc; k0 += 32) {
        __syncthreads();
        {
            int row = t >> 2, ko = (t & 3) << 3;
            gload16(A + (size_t)(m0 + row) * Cc + k0 + ko, As + t * 8);
            gload16(W + (size_t)(n0 + row) * Cc + k0 + ko, Bs + t * 8);
        }
        __syncthreads();
        bf16x8 af[2], bfr[2];
        #pragma unroll
        for (int i = 0; i < 2; ++i)
            af[i] = *(const bf16x8*)(As + ((wr * 32 + i * 16 + l15) * 32 + l4 * 8));
        #pragma unroll
        for (int j = 0; j < 2; ++j)
            bfr[j] = *(const bf16x8*)(Bs + ((wc * 32 + j * 16 + l15) * 32 + l4 * 8));
        #pragma unroll
        for (int i = 0; i < 2; ++i)
            #pragma unroll
            for (int j = 0; j < 2; ++j)
                acc[i][j] = __builtin_amdgcn_mfma_f32_16x16x32_bf16(af[i], bfr[j], acc[i][j], 0, 0, 0);
    }

    const int r0 = wr * 32 + (l4 << 2);
    const int c0 = wc * 32 + l15;
    #pragma unroll
    for (int i = 0; i < 2; ++i)
        #pragma unroll
        for (int j = 0; j < 2; ++j)
            #pragma unroll
            for (int r = 0; r < 4; ++r)
                outp[(size_t)(m0 + r0 + i * 16 + r) * Cc + n0 + c0 + j * 16] = acc[i][j][r];
}

// ---------------------------------------------------------------------------
// MFMA causal flash attention. 4 waves x 32 q-rows = 128 rows/block sharing
// one 32 KB K+V dbuf. Counted vmcnt(4). Split-K on 128-row chunks:
// c<4 unsplit, c=4..9 2-way, c>=10 3-way. 34 LPT jobs/bh, grid 32x34.
// ---------------------------------------------------------------------------
__device__ __constant__ unsigned char JOBS[34] = {
    61, 62,                                  // 11 tiles
    60, 56, 57, 58, 54, 36, 37,              // 10
    52, 53, 49, 50, 32, 33,                  // 9
    48, 44, 45, 46, 42, 28, 29, 12,          // 8
    40, 41, 24, 25,                          // 7
    20, 21, 8,                               // 6
    16, 17,                                  // 5
    4, 0                                     // 4, 2
};

__global__ __launch_bounds__(256)
void attn_mfma(const unsigned short* __restrict__ Q,
               const unsigned short* __restrict__ K,
               const unsigned short* __restrict__ Vt,
               unsigned short* __restrict__ Y,
               unsigned short* __restrict__ P1,   // p=1 partials, q in [512,2048)
               unsigned short* __restrict__ P2,   // p=2 partials, q in [1280,2048)
               float* __restrict__ mlf) {         // m[3][32][1536], l[3][32][1536]
    __shared__ unsigned short Ks[2][64 * 64];  // [buf][key][d]   (swizzled)
    __shared__ unsigned short Vs[2][64 * 64];  // [buf][d][key]   (swizzled)

    const int t = threadIdx.x, lane = t & 63, w = t >> 6;   // w = 0..3
    const int l31 = lane & 31, h = lane >> 5;
    const int bh = blockIdx.x;
    const int bb = bh >> 4, hh = bh & 15;

    const unsigned char job = JOBS[blockIdx.y];
    const int c = job >> 2, p = job & 3;
    const int n = 2 * c + 2;                       // tiles in chunk
    const int npart = c < 4 ? 1 : (c < 10 ? 2 : 3);
    const int kb0 = p * n / npart;
    const int kb1 = (p + 1) * n / npart;

    const int qbase = c * 128 + w * 32;
    const int q = qbase + l31;

    const unsigned short* Qp = Q + (size_t)bh * Tc * Dc;
    const unsigned short* Kp = K + (size_t)bh * Tc * Dc;
    const unsigned short* Vp = Vt + (size_t)bh * Dc * Tc;

    bf16x8 qf[4];
    #pragma unroll
    for (int kc = 0; kc < 4; ++kc)
        qf[kc] = *(const bf16x8*)(Qp + (size_t)q * 64 + kc * 16 + h * 8);

    f32x16 ot[2] = {};          // O^T: rows d=dt*32+(r&3)+8*(r>>2)+4h, col q
    float m = -INFINITY, lsum = 0.f;

    auto stage = [&](int kb, int buf) {
        #pragma unroll
        for (int it = 0; it < 2; ++it) {
            int idx = t + it * 256;           // 0..511
            int row = idx >> 3, slot = idx & 7;
            int ss = slot ^ (row & 7);        // pre-swizzled source
            gload16(Kp + (size_t)(kb * 64 + row) * 64 + ss * 8, &Ks[buf][idx * 8]);
            gload16(Vp + (size_t)row * Tc + kb * 64 + ss * 8, &Vs[buf][idx * 8]);
        }
    };

    stage(kb0, 0);
    if (kb0 + 1 < kb1) stage(kb0 + 1, 1);

    for (int kb = kb0; kb < kb1; ++kb) {
        const int cur = (kb - kb0) & 1;
        if (kb + 1 < kb1) asm volatile("s_waitcnt vmcnt(4)" ::: "memory");
        else              asm volatile("s_waitcnt vmcnt(0)" ::: "memory");
        SBAR();

        const bool active = (kb * 64 <= qbase + 31);
        if (active) {
            // ---- S^T = K @ Q^T  (log2 domain; 2 key-tiles of 32) ----
            f32x16 st[2] = {};
            __builtin_amdgcn_s_setprio(1);
            #pragma unroll
            for (int nt = 0; nt < 2; ++nt) {
                int key = nt * 32 + l31;
                #pragma unroll
                for (int kc = 0; kc < 4; ++kc) {
                    int boff = (kc * 32 + h * 16) ^ ((key & 7) << 4);
                    bf16x8 kf = *(const bf16x8*)(&Ks[cur][((key << 7) + boff) >> 1]);
                    st[nt] = __builtin_amdgcn_mfma_f32_32x32x16_bf16(kf, qf[kc], st[nt], 0, 0, 0);
                }
            }
            __builtin_amdgcn_s_setprio(0);

            if (kb * 64 + 63 > qbase) {  // causal mask (diagonal region)
                #pragma unroll
                for (int nt = 0; nt < 2; ++nt)
                    #pragma unroll
                    for (int r = 0; r < 16; ++r) {
                        int key = kb * 64 + nt * 32 + (r & 3) + 8 * (r >> 2) + 4 * h;
                        if (key > q) st[nt][r] = -1e30f;
                    }
            }

            float mx[16];
            #pragma unroll
            for (int r = 0; r < 16; ++r) mx[r] = fmaxf(st[0][r], st[1][r]);
            #pragma unroll
            for (int s2 = 8; s2 > 0; s2 >>= 1)
                #pragma unroll
                for (int r = 0; r < s2; ++r) mx[r] = fmaxf(mx[r], mx[r + s2]);
            float tmax = fmaxf(mx[0], __shfl_xor(mx[0], 32));

            if (__any(tmax > m + 8.f)) {
                float mn = fmaxf(m, tmax);
                float al = EXP2(m - mn);
                m = mn;
                lsum *= al;
                #pragma unroll
                for (int dt = 0; dt < 2; ++dt)
                    #pragma unroll
                    for (int r = 0; r < 16; ++r) ot[dt][r] *= al;
            }

            float psa[4] = {0.f, 0.f, 0.f, 0.f};
            #pragma unroll
            for (int nt = 0; nt < 2; ++nt)
                #pragma unroll
                for (int r = 0; r < 16; ++r) {
                    float pv = EXP2(st[nt][r] - m);
                    st[nt][r] = pv;
                    psa[r & 3] += pv;
                }
            lsum += (psa[0] + psa[1]) + (psa[2] + psa[3]);

            #pragma unroll
            for (int nt = 0; nt < 2; ++nt) {
                unsigned a0 = cvt_pk_bf16(st[nt][0],  st[nt][1]);
                unsigned b0 = cvt_pk_bf16(st[nt][4],  st[nt][5]);
                unsigned a1 = cvt_pk_bf16(st[nt][2],  st[nt][3]);
                unsigned b1 = cvt_pk_bf16(st[nt][6],  st[nt][7]);
                int2v r0 = __builtin_amdgcn_permlane32_swap((int)a0, (int)b0, false, false);
                int2v r1 = __builtin_amdgcn_permlane32_swap((int)a1, (int)b1, false, false);
                union { unsigned u[4]; bf16x8 v; } pf0, pf1;
                pf0.u[0] = r0.x; pf0.u[1] = r1.x; pf0.u[2] = r0.y; pf0.u[3] = r1.y;
                unsigned c0 = cvt_pk_bf16(st[nt][8],  st[nt][9]);
                unsigned d0 = cvt_pk_bf16(st[nt][12], st[nt][13]);
                unsigned c1 = cvt_pk_bf16(st[nt][10], st[nt][11]);
                unsigned d1 = cvt_pk_bf16(st[nt][14], st[nt][15]);
                int2v r2 = __builtin_amdgcn_permlane32_swap((int)c0, (int)d0, false, false);
                int2v r3 = __builtin_amdgcn_permlane32_swap((int)c1, (int)d1, false, false);
                pf1.u[0] = r2.x; pf1.u[1] = r3.x; pf1.u[2] = r2.y; pf1.u[3] = r3.y;

                __builtin_amdgcn_s_setprio(1);
                #pragma unroll
                for (int dt = 0; dt < 2; ++dt) {
                    int d = dt * 32 + l31;
                    int v0off = (nt * 64 + h * 16) ^ ((d & 7) << 4);
                    bf16x8 vf0 = *(const bf16x8*)(&Vs[cur][((d << 7) + v0off) >> 1]);
                    ot[dt] = __builtin_amdgcn_mfma_f32_32x32x16_bf16(vf0, pf0.v, ot[dt], 0, 0, 0);
                }
                #pragma unroll
                for (int dt = 0; dt < 2; ++dt) {
                    int d = dt * 32 + l31;
                    int v1off = (nt * 64 + 32 + h * 16) ^ ((d & 7) << 4);
                    bf16x8 vf1 = *(const bf16x8*)(&Vs[cur][((d << 7) + v1off) >> 1]);
                    ot[dt] = __builtin_amdgcn_mfma_f32_32x32x16_bf16(vf1, pf1.v, ot[dt], 0, 0, 0);
                }
                __builtin_amdgcn_s_setprio(0);
            }
        }

        SBAR();
        if (kb + 2 < kb1) stage(kb + 2, cur);
    }

    // ---- epilogue ----
    float lf = lsum + __shfl_xor(lsum, 32);
    unsigned short* dst;
    size_t base;
    if (npart == 1 || p == 0) {
        dst = Y;  base = ((size_t)bb * Tc + q) * Cc + hh * 64;
    } else if (p == 1) {
        dst = P1; base = ((size_t)(bb * 1536 + (q - 512))) * Cc + hh * 64;
    } else {
        dst = P2; base = ((size_t)(bb * 768 + (q - 1280))) * Cc + hh * 64;
    }
    float inv = (npart == 1) ? 1.f / lf : 1.f;
    #pragma unroll
    for (int dt = 0; dt < 2; ++dt)
        #pragma unroll
        for (int rg = 0; rg < 4; ++rg) {
            int d0 = dt * 32 + rg * 8 + 4 * h;
            ushort4 s4;
            s4.x = f2bf(ot[dt][rg * 4 + 0] * inv);
            s4.y = f2bf(ot[dt][rg * 4 + 1] * inv);
            s4.z = f2bf(ot[dt][rg * 4 + 2] * inv);
            s4.w = f2bf(ot[dt][rg * 4 + 3] * inv);
            *(ushort4*)(dst + base + d0) = s4;
        }
    if (npart > 1 && h == 0) {
        int mi = p * 49152 + bh * 1536 + (q - 512);
        mlf[mi]          = m;
        mlf[147456 + mi] = lf;
    }
}

// ---------------------------------------------------------------------------
__global__ __launch_bounds__(256)
void attn_combine(unsigned short* __restrict__ Y,
                  const unsigned short* __restrict__ P1,
                  const unsigned short* __restrict__ P2,
                  const float* __restrict__ mlf) {
    int tid = blockIdx.x * 256 + threadIdx.x;    // 0 .. 393215
    int rowIdx = tid >> 7;                        // bb*1536 + (q-512)
    int col8 = (tid & 127) * 8;
    int bb = rowIdx / 1536, qoff = rowIdx % 1536;
    int q = 512 + qoff;
    int hh = col8 >> 6;
    int mi = (bb * 16 + hh) * 1536 + qoff;
    bool three = q >= 1280;

    float m0 = mlf[mi],          l0 = mlf[147456 + mi];
    float m1 = mlf[49152 + mi],  l1 = mlf[196608 + mi];
    float m2 = three ? mlf[98304 + mi]  : -INFINITY;
    float l2 = three ? mlf[245760 + mi] : 0.f;

    float M = fmaxf(fmaxf(m0, m1), m2);
    float a0 = exp2f(m0 - M), a1 = exp2f(m1 - M);
    float a2 = three ? exp2f(m2 - M) : 0.f;
    float inv = 1.f / (l0 * a0 + l1 * a1 + l2 * a2);

    size_t offY = ((size_t)(bb * Tc + q)) * Cc + col8;
    size_t off1 = ((size_t)rowIdx) * Cc + col8;
    union { unsigned short u[8]; bf16x8 v; } y0, y1, y2, r;
    y0.v = *(const bf16x8*)(Y + offY);
    y1.v = *(const bf16x8*)(P1 + off1);
    if (three) {
        size_t off2 = ((size_t)(bb * 768 + (q - 1280))) * Cc + col8;
        y2.v = *(const bf16x8*)(P2 + off2);
    }
    #pragma unroll
    for (int j = 0; j < 8; ++j) {
        float acc = bf2f(y0.u[j]) * a0 + bf2f(y1.u[j]) * a1;
        if (three) acc += bf2f(y2.u[j]) * a2;
        r.u[j] = f2bf(acc * inv);
    }
    *(bf16x8*)(Y + offY) = r.v;
}

// ---------------------------------------------------------------------------
extern "C" void kernel_launch(void* const* d_in, const int* in_sizes, int n_in,
                              void* d_out, int out_size, void* d_ws, size_t ws_size,
                              hipStream_t stream) {
    const float* x  = (const float*)d_in[0];
    const float* Wq = (const float*)d_in[1];
    const float* Wk = (const float*)d_in[2];
    const float* Wv = (const float*)d_in[3];
    const float* Wo = (const float*)d_in[4];

    unsigned short* ws = (unsigned short*)d_ws;
    const size_t nX = (size_t)Mc * Cc;   // 4194304
    const size_t nW = (size_t)Cc * Cc;   // 1048576
    size_t off = 0;
    unsigned short* xb  = ws + off; off += nX;   // dead after gemm_qkv -> P1
    unsigned short* Wqb = ws + off; off += nW;   // dead -> P2 (with Wkb)
    unsigned short* Wkb = ws + off; off += nW;
    unsigned short* Wvb = ws + off; off += nW;   // dead -> mlf
    unsigned short* Wob = ws + off; off += nW;   // LIVE until gemm_out
    unsigned short* Qw  = ws + off; off += nX;
    unsigned short* Kw  = ws + off; off += nX;
    unsigned short* Vtw = ws + off; off += nX;
    unsigned short* Yb  = ws + off; off += nX;

    dim3 blk(256);
    cast_bf16<<<dim3((int)(nX / 8 / 256)), blk, 0, stream>>>(x, xb, (int)(nX / 8));
    cast_w4<<<dim3(512, 4), blk, 0, stream>>>(Wq, Wk, Wv, Wo, Wqb, Wkb, Wvb, Wob);

    gemm_qkv<<<dim3(Mc / 256, 12), dim3(512), 0, stream>>>(xb, Wqb, Wkb, Wvb, Qw, Kw, Vtw);

    unsigned short* P1 = xb;
    unsigned short* P2 = Wqb;            // spans Wqb+Wkb
    float* mlf = (float*)Wvb;
    attn_mfma<<<dim3(Bc * Hc, 34), blk, 0, stream>>>(Qw, Kw, Vtw, Yb, P1, P2, mlf);
    attn_combine<<<dim3(1536), blk, 0, stream>>>(Yb, P1, P2, mlf);

    gemm_out<<<dim3(Mc / 64, Cc / 64), blk, 0, stream>>>(Yb, Wob, (float*)d_out);
}

// Round 13
// 119.458 us; speedup vs baseline: 1.1668x; 1.1668x over previous
//
#include <hip/hip_runtime.h>
#include <math.h>

typedef short bf16x8 __attribute__((ext_vector_type(8)));
typedef float f32x4 __attribute__((ext_vector_type(4)));
typedef float f32x16 __attribute__((ext_vector_type(16)));
typedef int int2v __attribute__((ext_vector_type(2)));

constexpr int Bc = 2, Tc = 2048, Cc = 1024, Hc = 16, Dc = 64;
constexpr int Mc = Bc * Tc;  // 4096

#if __has_builtin(__builtin_amdgcn_exp2f)
#define EXP2(x) __builtin_amdgcn_exp2f(x)
#else
#define EXP2(x) exp2f(x)
#endif

#define SBAR() do { asm volatile("" ::: "memory"); \
                    __builtin_amdgcn_s_barrier();   \
                    asm volatile("" ::: "memory"); } while (0)

__device__ __forceinline__ unsigned short f2bf(float f) {
    union { float f; unsigned u; } v; v.f = f;
    unsigned r = v.u + 0x7fffu + ((v.u >> 16) & 1u);  // RNE
    return (unsigned short)(r >> 16);
}

__device__ __forceinline__ float bf2f(unsigned short u) {
    union { unsigned u; float f; } v; v.u = (unsigned)u << 16; return v.f;
}

__device__ __forceinline__ unsigned cvt_pk_bf16(float lo, float hi) {
    unsigned r;
    asm("v_cvt_pk_bf16_f32 %0, %1, %2" : "=v"(r) : "v"(lo), "v"(hi));
    return r;
}

__device__ __forceinline__ void gload16(const void* g, void* l) {
    __builtin_amdgcn_global_load_lds(
        (const __attribute__((address_space(1))) void*)g,
        (__attribute__((address_space(3))) void*)l, 16, 0, 0);
}

// ---------------------------------------------------------------------------
__global__ __launch_bounds__(256)
void cast_bf16(const float* __restrict__ in, unsigned short* __restrict__ out, int n8) {
    int i = blockIdx.x * 256 + threadIdx.x;
    if (i >= n8) return;
    const float4* p = (const float4*)in;
    float4 a = p[i * 2], b = p[i * 2 + 1];
    union { unsigned short u[8]; bf16x8 v; } r;
    r.u[0] = f2bf(a.x); r.u[1] = f2bf(a.y); r.u[2] = f2bf(a.z); r.u[3] = f2bf(a.w);
    r.u[4] = f2bf(b.x); r.u[5] = f2bf(b.y); r.u[6] = f2bf(b.z); r.u[7] = f2bf(b.w);
    *(bf16x8*)(out + i * 8) = r.v;
}

__global__ __launch_bounds__(256)
void cast_w4(const float* __restrict__ a, const float* __restrict__ b,
             const float* __restrict__ c, const float* __restrict__ d,
             unsigned short* __restrict__ oa, unsigned short* __restrict__ ob,
             unsigned short* __restrict__ oc, unsigned short* __restrict__ od) {
    const float* src = blockIdx.y == 0 ? a : blockIdx.y == 1 ? b : blockIdx.y == 2 ? c : d;
    unsigned short* dst = blockIdx.y == 0 ? oa : blockIdx.y == 1 ? ob : blockIdx.y == 2 ? oc : od;
    int i = blockIdx.x * 256 + threadIdx.x;
    const float4* p = (const float4*)src;
    float4 x = p[i * 2], y = p[i * 2 + 1];
    union { unsigned short u[8]; bf16x8 v; } r;
    r.u[0] = f2bf(x.x); r.u[1] = f2bf(x.y); r.u[2] = f2bf(x.z); r.u[3] = f2bf(x.w);
    r.u[4] = f2bf(y.x); r.u[5] = f2bf(y.y); r.u[6] = f2bf(y.z); r.u[7] = f2bf(y.w);
    *(bf16x8*)(dst + i * 8) = r.v;
}

// ---------------------------------------------------------------------------
// Fused QKV GEMM (NT): 128x128 tile, BK=32, 4 waves, 768 blocks -- R4
// geometry + the guide's verified minimum 2-phase pipeline (T3 recipe):
// per K-step { STAGE(buf^1, kt+1); ds_read(buf)+MFMA; vmcnt(0); barrier }.
// Stage issued BEFORE compute so loads land under the MFMA phase; ONE
// barrier per step (R4 had two + in-loop drain before compute).
// blockIdx.y: 0..7 -> Q (scaled 0.125*log2e), 8..15 -> K, 16..23 -> V^T.
// ---------------------------------------------------------------------------
__global__ __launch_bounds__(256)
void gemm_qkv(const unsigned short* __restrict__ A,
              const unsigned short* __restrict__ Wq,
              const unsigned short* __restrict__ Wk,
              const unsigned short* __restrict__ Wv,
              unsigned short* __restrict__ Qo,
              unsigned short* __restrict__ Ko,
              unsigned short* __restrict__ Vo) {
    __shared__ unsigned short As[2][128 * 32];
    __shared__ unsigned short Bs[2][128 * 32];
    const int t = threadIdx.x;
    const int lane = t & 63, l15 = lane & 15, l4 = lane >> 4;
    const int w = t >> 6, wr = w >> 1, wc = w & 1;
    const int seg = blockIdx.y >> 3;              // 0=Q 1=K 2=V
    const unsigned short* W = seg == 0 ? Wq : seg == 1 ? Wk : Wv;
    const int m0 = blockIdx.x * 128, n0 = (blockIdx.y & 7) * 128;

    f32x4 acc[4][4] = {};

    auto stageg = [&](int kt, int buf) {
        const int k0 = kt * 32;
        #pragma unroll
        for (int it = 0; it < 2; ++it) {
            int c = t + it * 256;
            int row = c >> 2, ko = (c & 3) << 3;
            gload16(A + (size_t)(m0 + row) * Cc + k0 + ko, As[buf] + c * 8);
            gload16(W + (size_t)(n0 + row) * Cc + k0 + ko, Bs[buf] + c * 8);
        }
    };

    // prologue: tile 0 staged and published
    stageg(0, 0);
    asm volatile("s_waitcnt vmcnt(0)" ::: "memory");
    SBAR();

    const int NKT = Cc / 32;   // 32
    int cur = 0;
    for (int kt = 0; kt < NKT; ++kt) {
        if (kt + 1 < NKT) stageg(kt + 1, cur ^ 1);   // issue next tile FIRST

        bf16x8 af[4], bfr[4];
        #pragma unroll
        for (int i = 0; i < 4; ++i)
            af[i] = *(const bf16x8*)(As[cur] + ((wr * 64 + i * 16 + l15) * 32 + l4 * 8));
        #pragma unroll
        for (int j = 0; j < 4; ++j)
            bfr[j] = *(const bf16x8*)(Bs[cur] + ((wc * 64 + j * 16 + l15) * 32 + l4 * 8));
        #pragma unroll
        for (int i = 0; i < 4; ++i)
            #pragma unroll
            for (int j = 0; j < 4; ++j)
                acc[i][j] = __builtin_amdgcn_mfma_f32_16x16x32_bf16(af[i], bfr[j], acc[i][j], 0, 0, 0);

        asm volatile("s_waitcnt vmcnt(0)" ::: "memory");  // next tile landed
        SBAR();                                           // all waves done w/ cur
        cur ^= 1;
    }

    const float qscale = 0.18033688011112042f;  // 0.125 * log2(e)
    const int r0 = wr * 64 + (l4 << 2);
    const int c0 = wc * 64 + l15;
    #pragma unroll
    for (int i = 0; i < 4; ++i)
        #pragma unroll
        for (int j = 0; j < 4; ++j)
            #pragma unroll
            for (int r = 0; r < 4; ++r) {
                int row = m0 + r0 + i * 16 + r;
                int col = n0 + c0 + j * 16;
                float v = acc[i][j][r];
                int bb = row >> 11, tt = row & (Tc - 1);
                int hh = col >> 6, dd = col & 63;
                if (seg == 0)
                    Qo[((((size_t)bb * Hc + hh) * Tc + tt) << 6) + dd] = f2bf(v * qscale);
                else if (seg == 1)
                    Ko[((((size_t)bb * Hc + hh) * Tc + tt) << 6) + dd] = f2bf(v);
                else
                    Vo[(((size_t)bb * Hc + hh) * Dc + dd) * Tc + tt] = f2bf(v);
            }
}

// ---------------------------------------------------------------------------
// Out-projection GEMM (NT): 64x64 tile, 1024 blocks (4/CU), fp32 out [M,C].
// ---------------------------------------------------------------------------
__global__ __launch_bounds__(256)
void gemm_out(const unsigned short* __restrict__ A,
              const unsigned short* __restrict__ W,
              float* __restrict__ outp) {
    __shared__ unsigned short As[64 * 32];
    __shared__ unsigned short Bs[64 * 32];
    const int t = threadIdx.x;
    const int lane = t & 63, l15 = lane & 15, l4 = lane >> 4;
    const int w = t >> 6, wr = w >> 1, wc = w & 1;
    const int m0 = blockIdx.x * 64, n0 = blockIdx.y * 64;

    f32x4 acc[2][2] = {};

    for (int k0 = 0; k0 < Cc; k0 += 32) {
        __syncthreads();
        {
            int row = t >> 2, ko = (t & 3) << 3;
            gload16(A + (size_t)(m0 + row) * Cc + k0 + ko, As + t * 8);
            gload16(W + (size_t)(n0 + row) * Cc + k0 + ko, Bs + t * 8);
        }
        __syncthreads();
        bf16x8 af[2], bfr[2];
        #pragma unroll
        for (int i = 0; i < 2; ++i)
            af[i] = *(const bf16x8*)(As + ((wr * 32 + i * 16 + l15) * 32 + l4 * 8));
        #pragma unroll
        for (int j = 0; j < 2; ++j)
            bfr[j] = *(const bf16x8*)(Bs + ((wc * 32 + j * 16 + l15) * 32 + l4 * 8));
        #pragma unroll
        for (int i = 0; i < 2; ++i)
            #pragma unroll
            for (int j = 0; j < 2; ++j)
                acc[i][j] = __builtin_amdgcn_mfma_f32_16x16x32_bf16(af[i], bfr[j], acc[i][j], 0, 0, 0);
    }

    const int r0 = wr * 32 + (l4 << 2);
    const int c0 = wc * 32 + l15;
    #pragma unroll
    for (int i = 0; i < 2; ++i)
        #pragma unroll
        for (int j = 0; j < 2; ++j)
            #pragma unroll
            for (int r = 0; r < 4; ++r)
                outp[(size_t)(m0 + r0 + i * 16 + r) * Cc + n0 + c0 + j * 16] = acc[i][j][r];
}

// ---------------------------------------------------------------------------
// MFMA causal flash attention. 4 waves x 32 q-rows = 128 rows/block sharing
// one 32 KB K+V dbuf. Counted vmcnt(4). Split-K on 128-row chunks:
// c<4 unsplit, c=4..9 2-way, c>=10 3-way. 34 LPT jobs/bh, grid 32x34.
// ---------------------------------------------------------------------------
__device__ __constant__ unsigned char JOBS[34] = {
    61, 62,                                  // 11 tiles
    60, 56, 57, 58, 54, 36, 37,              // 10
    52, 53, 49, 50, 32, 33,                  // 9
    48, 44, 45, 46, 42, 28, 29, 12,          // 8
    40, 41, 24, 25,                          // 7
    20, 21, 8,                               // 6
    16, 17,                                  // 5
    4, 0                                     // 4, 2
};

__global__ __launch_bounds__(256)
void attn_mfma(const unsigned short* __restrict__ Q,
               const unsigned short* __restrict__ K,
               const unsigned short* __restrict__ Vt,
               unsigned short* __restrict__ Y,
               unsigned short* __restrict__ P1,   // p=1 partials, q in [512,2048)
               unsigned short* __restrict__ P2,   // p=2 partials, q in [1280,2048)
               float* __restrict__ mlf) {         // m[3][32][1536], l[3][32][1536]
    __shared__ unsigned short Ks[2][64 * 64];  // [buf][key][d]   (swizzled)
    __shared__ unsigned short Vs[2][64 * 64];  // [buf][d][key]   (swizzled)

    const int t = threadIdx.x, lane = t & 63, w = t >> 6;   // w = 0..3
    const int l31 = lane & 31, h = lane >> 5;
    const int bh = blockIdx.x;
    const int bb = bh >> 4, hh = bh & 15;

    const unsigned char job = JOBS[blockIdx.y];
    const int c = job >> 2, p = job & 3;
    const int n = 2 * c + 2;                       // tiles in chunk
    const int npart = c < 4 ? 1 : (c < 10 ? 2 : 3);
    const int kb0 = p * n / npart;
    const int kb1 = (p + 1) * n / npart;

    const int qbase = c * 128 + w * 32;
    const int q = qbase + l31;

    const unsigned short* Qp = Q + (size_t)bh * Tc * Dc;
    const unsigned short* Kp = K + (size_t)bh * Tc * Dc;
    const unsigned short* Vp = Vt + (size_t)bh * Dc * Tc;

    bf16x8 qf[4];
    #pragma unroll
    for (int kc = 0; kc < 4; ++kc)
        qf[kc] = *(const bf16x8*)(Qp + (size_t)q * 64 + kc * 16 + h * 8);

    f32x16 ot[2] = {};          // O^T: rows d=dt*32+(r&3)+8*(r>>2)+4h, col q
    float m = -INFINITY, lsum = 0.f;

    auto stage = [&](int kb, int buf) {
        #pragma unroll
        for (int it = 0; it < 2; ++it) {
            int idx = t + it * 256;           // 0..511
            int row = idx >> 3, slot = idx & 7;
            int ss = slot ^ (row & 7);        // pre-swizzled source
            gload16(Kp + (size_t)(kb * 64 + row) * 64 + ss * 8, &Ks[buf][idx * 8]);
            gload16(Vp + (size_t)row * Tc + kb * 64 + ss * 8, &Vs[buf][idx * 8]);
        }
    };

    stage(kb0, 0);
    if (kb0 + 1 < kb1) stage(kb0 + 1, 1);

    for (int kb = kb0; kb < kb1; ++kb) {
        const int cur = (kb - kb0) & 1;
        if (kb + 1 < kb1) asm volatile("s_waitcnt vmcnt(4)" ::: "memory");
        else              asm volatile("s_waitcnt vmcnt(0)" ::: "memory");
        SBAR();

        const bool active = (kb * 64 <= qbase + 31);
        if (active) {
            // ---- S^T = K @ Q^T  (log2 domain; 2 key-tiles of 32) ----
            f32x16 st[2] = {};
            __builtin_amdgcn_s_setprio(1);
            #pragma unroll
            for (int nt = 0; nt < 2; ++nt) {
                int key = nt * 32 + l31;
                #pragma unroll
                for (int kc = 0; kc < 4; ++kc) {
                    int boff = (kc * 32 + h * 16) ^ ((key & 7) << 4);
                    bf16x8 kf = *(const bf16x8*)(&Ks[cur][((key << 7) + boff) >> 1]);
                    st[nt] = __builtin_amdgcn_mfma_f32_32x32x16_bf16(kf, qf[kc], st[nt], 0, 0, 0);
                }
            }
            __builtin_amdgcn_s_setprio(0);

            if (kb * 64 + 63 > qbase) {  // causal mask (diagonal region)
                #pragma unroll
                for (int nt = 0; nt < 2; ++nt)
                    #pragma unroll
                    for (int r = 0; r < 16; ++r) {
                        int key = kb * 64 + nt * 32 + (r & 3) + 8 * (r >> 2) + 4 * h;
                        if (key > q) st[nt][r] = -1e30f;
                    }
            }

            float mx[16];
            #pragma unroll
            for (int r = 0; r < 16; ++r) mx[r] = fmaxf(st[0][r], st[1][r]);
            #pragma unroll
            for (int s2 = 8; s2 > 0; s2 >>= 1)
                #pragma unroll
                for (int r = 0; r < s2; ++r) mx[r] = fmaxf(mx[r], mx[r + s2]);
            float tmax = fmaxf(mx[0], __shfl_xor(mx[0], 32));

            if (__any(tmax > m + 8.f)) {
                float mn = fmaxf(m, tmax);
                float al = EXP2(m - mn);
                m = mn;
                lsum *= al;
                #pragma unroll
                for (int dt = 0; dt < 2; ++dt)
                    #pragma unroll
                    for (int r = 0; r < 16; ++r) ot[dt][r] *= al;
            }

            float psa[4] = {0.f, 0.f, 0.f, 0.f};
            #pragma unroll
            for (int nt = 0; nt < 2; ++nt)
                #pragma unroll
                for (int r = 0; r < 16; ++r) {
                    float pv = EXP2(st[nt][r] - m);
                    st[nt][r] = pv;
                    psa[r & 3] += pv;
                }
            lsum += (psa[0] + psa[1]) + (psa[2] + psa[3]);

            #pragma unroll
            for (int nt = 0; nt < 2; ++nt) {
                unsigned a0 = cvt_pk_bf16(st[nt][0],  st[nt][1]);
                unsigned b0 = cvt_pk_bf16(st[nt][4],  st[nt][5]);
                unsigned a1 = cvt_pk_bf16(st[nt][2],  st[nt][3]);
                unsigned b1 = cvt_pk_bf16(st[nt][6],  st[nt][7]);
                int2v r0 = __builtin_amdgcn_permlane32_swap((int)a0, (int)b0, false, false);
                int2v r1 = __builtin_amdgcn_permlane32_swap((int)a1, (int)b1, false, false);
                union { unsigned u[4]; bf16x8 v; } pf0, pf1;
                pf0.u[0] = r0.x; pf0.u[1] = r1.x; pf0.u[2] = r0.y; pf0.u[3] = r1.y;
                unsigned c0 = cvt_pk_bf16(st[nt][8],  st[nt][9]);
                unsigned d0 = cvt_pk_bf16(st[nt][12], st[nt][13]);
                unsigned c1 = cvt_pk_bf16(st[nt][10], st[nt][11]);
                unsigned d1 = cvt_pk_bf16(st[nt][14], st[nt][15]);
                int2v r2 = __builtin_amdgcn_permlane32_swap((int)c0, (int)d0, false, false);
                int2v r3 = __builtin_amdgcn_permlane32_swap((int)c1, (int)d1, false, false);
                pf1.u[0] = r2.x; pf1.u[1] = r3.x; pf1.u[2] = r2.y; pf1.u[3] = r3.y;

                __builtin_amdgcn_s_setprio(1);
                #pragma unroll
                for (int dt = 0; dt < 2; ++dt) {
                    int d = dt * 32 + l31;
                    int v0off = (nt * 64 + h * 16) ^ ((d & 7) << 4);
                    bf16x8 vf0 = *(const bf16x8*)(&Vs[cur][((d << 7) + v0off) >> 1]);
                    ot[dt] = __builtin_amdgcn_mfma_f32_32x32x16_bf16(vf0, pf0.v, ot[dt], 0, 0, 0);
                }
                #pragma unroll
                for (int dt = 0; dt < 2; ++dt) {
                    int d = dt * 32 + l31;
                    int v1off = (nt * 64 + 32 + h * 16) ^ ((d & 7) << 4);
                    bf16x8 vf1 = *(const bf16x8*)(&Vs[cur][((d << 7) + v1off) >> 1]);
                    ot[dt] = __builtin_amdgcn_mfma_f32_32x32x16_bf16(vf1, pf1.v, ot[dt], 0, 0, 0);
                }
                __builtin_amdgcn_s_setprio(0);
            }
        }

        SBAR();
        if (kb + 2 < kb1) stage(kb + 2, cur);
    }

    // ---- epilogue ----
    float lf = lsum + __shfl_xor(lsum, 32);
    unsigned short* dst;
    size_t base;
    if (npart == 1 || p == 0) {
        dst = Y;  base = ((size_t)bb * Tc + q) * Cc + hh * 64;
    } else if (p == 1) {
        dst = P1; base = ((size_t)(bb * 1536 + (q - 512))) * Cc + hh * 64;
    } else {
        dst = P2; base = ((size_t)(bb * 768 + (q - 1280))) * Cc + hh * 64;
    }
    float inv = (npart == 1) ? 1.f / lf : 1.f;
    #pragma unroll
    for (int dt = 0; dt < 2; ++dt)
        #pragma unroll
        for (int rg = 0; rg < 4; ++rg) {
            int d0 = dt * 32 + rg * 8 + 4 * h;
            ushort4 s4;
            s4.x = f2bf(ot[dt][rg * 4 + 0] * inv);
            s4.y = f2bf(ot[dt][rg * 4 + 1] * inv);
            s4.z = f2bf(ot[dt][rg * 4 + 2] * inv);
            s4.w = f2bf(ot[dt][rg * 4 + 3] * inv);
            *(ushort4*)(dst + base + d0) = s4;
        }
    if (npart > 1 && h == 0) {
        int mi = p * 49152 + bh * 1536 + (q - 512);
        mlf[mi]          = m;
        mlf[147456 + mi] = lf;
    }
}

// ---------------------------------------------------------------------------
__global__ __launch_bounds__(256)
void attn_combine(unsigned short* __restrict__ Y,
                  const unsigned short* __restrict__ P1,
                  const unsigned short* __restrict__ P2,
                  const float* __restrict__ mlf) {
    int tid = blockIdx.x * 256 + threadIdx.x;    // 0 .. 393215
    int rowIdx = tid >> 7;                        // bb*1536 + (q-512)
    int col8 = (tid & 127) * 8;
    int bb = rowIdx / 1536, qoff = rowIdx % 1536;
    int q = 512 + qoff;
    int hh = col8 >> 6;
    int mi = (bb * 16 + hh) * 1536 + qoff;
    bool three = q >= 1280;

    float m0 = mlf[mi],          l0 = mlf[147456 + mi];
    float m1 = mlf[49152 + mi],  l1 = mlf[196608 + mi];
    float m2 = three ? mlf[98304 + mi]  : -INFINITY;
    float l2 = three ? mlf[245760 + mi] : 0.f;

    float M = fmaxf(fmaxf(m0, m1), m2);
    float a0 = exp2f(m0 - M), a1 = exp2f(m1 - M);
    float a2 = three ? exp2f(m2 - M) : 0.f;
    float inv = 1.f / (l0 * a0 + l1 * a1 + l2 * a2);

    size_t offY = ((size_t)(bb * Tc + q)) * Cc + col8;
    size_t off1 = ((size_t)rowIdx) * Cc + col8;
    union { unsigned short u[8]; bf16x8 v; } y0, y1, y2, r;
    y0.v = *(const bf16x8*)(Y + offY);
    y1.v = *(const bf16x8*)(P1 + off1);
    if (three) {
        size_t off2 = ((size_t)(bb * 768 + (q - 1280))) * Cc + col8;
        y2.v = *(const bf16x8*)(P2 + off2);
    }
    #pragma unroll
    for (int j = 0; j < 8; ++j) {
        float acc = bf2f(y0.u[j]) * a0 + bf2f(y1.u[j]) * a1;
        if (three) acc += bf2f(y2.u[j]) * a2;
        r.u[j] = f2bf(acc * inv);
    }
    *(bf16x8*)(Y + offY) = r.v;
}

// ---------------------------------------------------------------------------
extern "C" void kernel_launch(void* const* d_in, const int* in_sizes, int n_in,
                              void* d_out, int out_size, void* d_ws, size_t ws_size,
                              hipStream_t stream) {
    const float* x  = (const float*)d_in[0];
    const float* Wq = (const float*)d_in[1];
    const float* Wk = (const float*)d_in[2];
    const float* Wv = (const float*)d_in[3];
    const float* Wo = (const float*)d_in[4];

    unsigned short* ws = (unsigned short*)d_ws;
    const size_t nX = (size_t)Mc * Cc;   // 4194304
    const size_t nW = (size_t)Cc * Cc;   // 1048576
    size_t off = 0;
    unsigned short* xb  = ws + off; off += nX;   // dead after gemm_qkv -> P1
    unsigned short* Wqb = ws + off; off += nW;   // dead -> P2 (with Wkb)
    unsigned short* Wkb = ws + off; off += nW;
    unsigned short* Wvb = ws + off; off += nW;   // dead -> mlf
    unsigned short* Wob = ws + off; off += nW;   // LIVE until gemm_out
    unsigned short* Qw  = ws + off; off += nX;
    unsigned short* Kw  = ws + off; off += nX;
    unsigned short* Vtw = ws + off; off += nX;
    unsigned short* Yb  = ws + off; off += nX;

    dim3 blk(256);
    cast_bf16<<<dim3((int)(nX / 8 / 256)), blk, 0, stream>>>(x, xb, (int)(nX / 8));
    cast_w4<<<dim3(512, 4), blk, 0, stream>>>(Wq, Wk, Wv, Wo, Wqb, Wkb, Wvb, Wob);

    gemm_qkv<<<dim3(Mc / 128, 24), blk, 0, stream>>>(xb, Wqb, Wkb, Wvb, Qw, Kw, Vtw);

    unsigned short* P1 = xb;
    unsigned short* P2 = Wqb;            // spans Wqb+Wkb
    float* mlf = (float*)Wvb;
    attn_mfma<<<dim3(Bc * Hc, 34), blk, 0, stream>>>(Qw, Kw, Vtw, Yb, P1, P2, mlf);
    attn_combine<<<dim3(1536), blk, 0, stream>>>(Yb, P1, P2, mlf);

    gemm_out<<<dim3(Mc / 64, Cc / 64), blk, 0, stream>>>(Yb, Wob, (float*)d_out);
}

// Round 14
// 119.322 us; speedup vs baseline: 1.1682x; 1.0011x over previous
//
#include <hip/hip_runtime.h>
#include <math.h>

typedef short bf16x8 __attribute__((ext_vector_type(8)));
typedef float f32x4 __attribute__((ext_vector_type(4)));
typedef float f32x16 __attribute__((ext_vector_type(16)));
typedef int int2v __attribute__((ext_vector_type(2)));

constexpr int Bc = 2, Tc = 2048, Cc = 1024, Hc = 16, Dc = 64;
constexpr int Mc = Bc * Tc;  // 4096

#if __has_builtin(__builtin_amdgcn_exp2f)
#define EXP2(x) __builtin_amdgcn_exp2f(x)
#else
#define EXP2(x) exp2f(x)
#endif

#define SBAR() do { asm volatile("" ::: "memory"); \
                    __builtin_amdgcn_s_barrier();   \
                    asm volatile("" ::: "memory"); } while (0)

__device__ __forceinline__ unsigned short f2bf(float f) {
    union { float f; unsigned u; } v; v.f = f;
    unsigned r = v.u + 0x7fffu + ((v.u >> 16) & 1u);  // RNE
    return (unsigned short)(r >> 16);
}

__device__ __forceinline__ float bf2f(unsigned short u) {
    union { unsigned u; float f; } v; v.u = (unsigned)u << 16; return v.f;
}

__device__ __forceinline__ unsigned cvt_pk_bf16(float lo, float hi) {
    unsigned r;
    asm("v_cvt_pk_bf16_f32 %0, %1, %2" : "=v"(r) : "v"(lo), "v"(hi));
    return r;
}

__device__ __forceinline__ void gload16(const void* g, void* l) {
    __builtin_amdgcn_global_load_lds(
        (const __attribute__((address_space(1))) void*)g,
        (__attribute__((address_space(3))) void*)l, 16, 0, 0);
}

// ---------------------------------------------------------------------------
// One fused cast launch: blocks 0..2047 cast x (4.2M elems); blocks
// 2048..4095 cast the 4 weights (512 blocks each).
// ---------------------------------------------------------------------------
__global__ __launch_bounds__(256)
void cast_all(const float* __restrict__ x,
              const float* __restrict__ wq, const float* __restrict__ wk,
              const float* __restrict__ wv, const float* __restrict__ wo,
              unsigned short* __restrict__ xo,
              unsigned short* __restrict__ oq, unsigned short* __restrict__ ok,
              unsigned short* __restrict__ ov, unsigned short* __restrict__ oo) {
    int bid = blockIdx.x;
    const float* src;
    unsigned short* dst;
    int i;
    if (bid < 2048) {
        src = x; dst = xo; i = bid * 256 + threadIdx.x;
    } else {
        int wsel = (bid - 2048) >> 9;
        src = wsel == 0 ? wq : wsel == 1 ? wk : wsel == 2 ? wv : wo;
        dst = wsel == 0 ? oq : wsel == 1 ? ok : wsel == 2 ? ov : oo;
        i = ((bid - 2048) & 511) * 256 + threadIdx.x;
    }
    const float4* p = (const float4*)src;
    float4 a = p[i * 2], b = p[i * 2 + 1];
    union { unsigned short u[8]; bf16x8 v; } r;
    r.u[0] = f2bf(a.x); r.u[1] = f2bf(a.y); r.u[2] = f2bf(a.z); r.u[3] = f2bf(a.w);
    r.u[4] = f2bf(b.x); r.u[5] = f2bf(b.y); r.u[6] = f2bf(b.z); r.u[7] = f2bf(b.w);
    *(bf16x8*)(dst + i * 8) = r.v;
}

// ---------------------------------------------------------------------------
// Fused QKV GEMM (NT) -- best-known config (R4/R11): 128x128 tile, BK=32,
// 4 waves, single-buffer 2-barrier loop, 768 blocks. V^T epilogue stores
// vectorized (4 consecutive tt at fixed dd are contiguous in [B,H,D,T]).
// blockIdx.y: 0..7 -> Q (scaled 0.125*log2e), 8..15 -> K, 16..23 -> V^T.
// ---------------------------------------------------------------------------
__global__ __launch_bounds__(256)
void gemm_qkv(const unsigned short* __restrict__ A,
              const unsigned short* __restrict__ Wq,
              const unsigned short* __restrict__ Wk,
              const unsigned short* __restrict__ Wv,
              unsigned short* __restrict__ Qo,
              unsigned short* __restrict__ Ko,
              unsigned short* __restrict__ Vo) {
    __shared__ unsigned short As[128 * 32];
    __shared__ unsigned short Bs[128 * 32];
    const int t = threadIdx.x;
    const int lane = t & 63, l15 = lane & 15, l4 = lane >> 4;
    const int w = t >> 6, wr = w >> 1, wc = w & 1;
    const int seg = blockIdx.y >> 3;              // 0=Q 1=K 2=V
    const unsigned short* W = seg == 0 ? Wq : seg == 1 ? Wk : Wv;
    const int m0 = blockIdx.x * 128, n0 = (blockIdx.y & 7) * 128;

    f32x4 acc[4][4] = {};

    for (int k0 = 0; k0 < Cc; k0 += 32) {
        __syncthreads();
        #pragma unroll
        for (int it = 0; it < 2; ++it) {
            int c = t + it * 256;
            int row = c >> 2, ko = (c & 3) << 3;
            gload16(A + (size_t)(m0 + row) * Cc + k0 + ko, As + c * 8);
            gload16(W + (size_t)(n0 + row) * Cc + k0 + ko, Bs + c * 8);
        }
        __syncthreads();
        bf16x8 af[4], bfr[4];
        #pragma unroll
        for (int i = 0; i < 4; ++i)
            af[i] = *(const bf16x8*)(As + ((wr * 64 + i * 16 + l15) * 32 + l4 * 8));
        #pragma unroll
        for (int j = 0; j < 4; ++j)
            bfr[j] = *(const bf16x8*)(Bs + ((wc * 64 + j * 16 + l15) * 32 + l4 * 8));
        #pragma unroll
        for (int i = 0; i < 4; ++i)
            #pragma unroll
            for (int j = 0; j < 4; ++j)
                acc[i][j] = __builtin_amdgcn_mfma_f32_16x16x32_bf16(af[i], bfr[j], acc[i][j], 0, 0, 0);
    }

    const float qscale = 0.18033688011112042f;  // 0.125 * log2(e)
    const int r0 = wr * 64 + (l4 << 2);
    const int c0 = wc * 64 + l15;
    if (seg == 2) {
        // V^T: rows tt0..tt0+3 contiguous in [B,H,D,T] -> one ushort4 store
        #pragma unroll
        for (int i = 0; i < 4; ++i) {
            int row0 = m0 + r0 + i * 16;
            int bb = row0 >> 11, tt0 = row0 & (Tc - 1);
            #pragma unroll
            for (int j = 0; j < 4; ++j) {
                int col = n0 + c0 + j * 16;
                int hh = col >> 6, dd = col & 63;
                ushort4 s4;
                s4.x = f2bf(acc[i][j][0]);
                s4.y = f2bf(acc[i][j][1]);
                s4.z = f2bf(acc[i][j][2]);
                s4.w = f2bf(acc[i][j][3]);
                *(ushort4*)(Vo + (((size_t)bb * Hc + hh) * Dc + dd) * Tc + tt0) = s4;
            }
        }
    } else {
        unsigned short* O = seg == 0 ? Qo : Ko;
        const float sc = seg == 0 ? qscale : 1.f;
        #pragma unroll
        for (int i = 0; i < 4; ++i)
            #pragma unroll
            for (int j = 0; j < 4; ++j)
                #pragma unroll
                for (int r = 0; r < 4; ++r) {
                    int row = m0 + r0 + i * 16 + r;
                    int col = n0 + c0 + j * 16;
                    int bb = row >> 11, tt = row & (Tc - 1);
                    int hh = col >> 6, dd = col & 63;
                    O[((((size_t)bb * Hc + hh) * Tc + tt) << 6) + dd] = f2bf(acc[i][j][r] * sc);
                }
    }
}

// ---------------------------------------------------------------------------
// Out-projection GEMM (NT): 64x64 tile, 1024 blocks (4/CU), fp32 out [M,C].
// ---------------------------------------------------------------------------
__global__ __launch_bounds__(256)
void gemm_out(const unsigned short* __restrict__ A,
              const unsigned short* __restrict__ W,
              float* __restrict__ outp) {
    __shared__ unsigned short As[64 * 32];
    __shared__ unsigned short Bs[64 * 32];
    const int t = threadIdx.x;
    const int lane = t & 63, l15 = lane & 15, l4 = lane >> 4;
    const int w = t >> 6, wr = w >> 1, wc = w & 1;
    const int m0 = blockIdx.x * 64, n0 = blockIdx.y * 64;

    f32x4 acc[2][2] = {};

    for (int k0 = 0; k0 < Cc; k0 += 32) {
        __syncthreads();
        {
            int row = t >> 2, ko = (t & 3) << 3;
            gload16(A + (size_t)(m0 + row) * Cc + k0 + ko, As + t * 8);
            gload16(W + (size_t)(n0 + row) * Cc + k0 + ko, Bs + t * 8);
        }
        __syncthreads();
        bf16x8 af[2], bfr[2];
        #pragma unroll
        for (int i = 0; i < 2; ++i)
            af[i] = *(const bf16x8*)(As + ((wr * 32 + i * 16 + l15) * 32 + l4 * 8));
        #pragma unroll
        for (int j = 0; j < 2; ++j)
            bfr[j] = *(const bf16x8*)(Bs + ((wc * 32 + j * 16 + l15) * 32 + l4 * 8));
        #pragma unroll
        for (int i = 0; i < 2; ++i)
            #pragma unroll
            for (int j = 0; j < 2; ++j)
                acc[i][j] = __builtin_amdgcn_mfma_f32_16x16x32_bf16(af[i], bfr[j], acc[i][j], 0, 0, 0);
    }

    const int r0 = wr * 32 + (l4 << 2);
    const int c0 = wc * 32 + l15;
    #pragma unroll
    for (int i = 0; i < 2; ++i)
        #pragma unroll
        for (int j = 0; j < 2; ++j)
            #pragma unroll
            for (int r = 0; r < 4; ++r)
                outp[(size_t)(m0 + r0 + i * 16 + r) * Cc + n0 + c0 + j * 16] = acc[i][j][r];
}

// ---------------------------------------------------------------------------
// MFMA causal flash attention. 4 waves x 32 q-rows = 128 rows/block sharing
// one 32 KB K+V dbuf. Counted vmcnt(4). Split-K on 128-row chunks:
// c<4 unsplit, c=4..9 2-way, c>=10 3-way. 34 LPT jobs/bh, grid 32x34.
// ---------------------------------------------------------------------------
__device__ __constant__ unsigned char JOBS[34] = {
    61, 62,                                  // 11 tiles
    60, 56, 57, 58, 54, 36, 37,              // 10
    52, 53, 49, 50, 32, 33,                  // 9
    48, 44, 45, 46, 42, 28, 29, 12,          // 8
    40, 41, 24, 25,                          // 7
    20, 21, 8,                               // 6
    16, 17,                                  // 5
    4, 0                                     // 4, 2
};

__global__ __launch_bounds__(256)
void attn_mfma(const unsigned short* __restrict__ Q,
               const unsigned short* __restrict__ K,
               const unsigned short* __restrict__ Vt,
               unsigned short* __restrict__ Y,
               unsigned short* __restrict__ P1,   // p=1 partials, q in [512,2048)
               unsigned short* __restrict__ P2,   // p=2 partials, q in [1280,2048)
               float* __restrict__ mlf) {         // m[3][32][1536], l[3][32][1536]
    __shared__ unsigned short Ks[2][64 * 64];  // [buf][key][d]   (swizzled)
    __shared__ unsigned short Vs[2][64 * 64];  // [buf][d][key]   (swizzled)

    const int t = threadIdx.x, lane = t & 63, w = t >> 6;   // w = 0..3
    const int l31 = lane & 31, h = lane >> 5;
    const int bh = blockIdx.x;
    const int bb = bh >> 4, hh = bh & 15;

    const unsigned char job = JOBS[blockIdx.y];
    const int c = job >> 2, p = job & 3;
    const int n = 2 * c + 2;                       // tiles in chunk
    const int npart = c < 4 ? 1 : (c < 10 ? 2 : 3);
    const int kb0 = p * n / npart;
    const int kb1 = (p + 1) * n / npart;

    const int qbase = c * 128 + w * 32;
    const int q = qbase + l31;

    const unsigned short* Qp = Q + (size_t)bh * Tc * Dc;
    const unsigned short* Kp = K + (size_t)bh * Tc * Dc;
    const unsigned short* Vp = Vt + (size_t)bh * Dc * Tc;

    bf16x8 qf[4];
    #pragma unroll
    for (int kc = 0; kc < 4; ++kc)
        qf[kc] = *(const bf16x8*)(Qp + (size_t)q * 64 + kc * 16 + h * 8);

    f32x16 ot[2] = {};          // O^T: rows d=dt*32+(r&3)+8*(r>>2)+4h, col q
    float m = -INFINITY, lsum = 0.f;

    auto stage = [&](int kb, int buf) {
        #pragma unroll
        for (int it = 0; it < 2; ++it) {
            int idx = t + it * 256;           // 0..511
            int row = idx >> 3, slot = idx & 7;
            int ss = slot ^ (row & 7);        // pre-swizzled source
            gload16(Kp + (size_t)(kb * 64 + row) * 64 + ss * 8, &Ks[buf][idx * 8]);
            gload16(Vp + (size_t)row * Tc + kb * 64 + ss * 8, &Vs[buf][idx * 8]);
        }
    };

    stage(kb0, 0);
    if (kb0 + 1 < kb1) stage(kb0 + 1, 1);

    for (int kb = kb0; kb < kb1; ++kb) {
        const int cur = (kb - kb0) & 1;
        if (kb + 1 < kb1) asm volatile("s_waitcnt vmcnt(4)" ::: "memory");
        else              asm volatile("s_waitcnt vmcnt(0)" ::: "memory");
        SBAR();

        const bool active = (kb * 64 <= qbase + 31);
        if (active) {
            // ---- S^T = K @ Q^T  (log2 domain; 2 key-tiles of 32) ----
            f32x16 st[2] = {};
            __builtin_amdgcn_s_setprio(1);
            #pragma unroll
            for (int nt = 0; nt < 2; ++nt) {
                int key = nt * 32 + l31;
                #pragma unroll
                for (int kc = 0; kc < 4; ++kc) {
                    int boff = (kc * 32 + h * 16) ^ ((key & 7) << 4);
                    bf16x8 kf = *(const bf16x8*)(&Ks[cur][((key << 7) + boff) >> 1]);
                    st[nt] = __builtin_amdgcn_mfma_f32_32x32x16_bf16(kf, qf[kc], st[nt], 0, 0, 0);
                }
            }
            __builtin_amdgcn_s_setprio(0);

            if (kb * 64 + 63 > qbase) {  // causal mask (diagonal region)
                #pragma unroll
                for (int nt = 0; nt < 2; ++nt)
                    #pragma unroll
                    for (int r = 0; r < 16; ++r) {
                        int key = kb * 64 + nt * 32 + (r & 3) + 8 * (r >> 2) + 4 * h;
                        if (key > q) st[nt][r] = -1e30f;
                    }
            }

            float mx[16];
            #pragma unroll
            for (int r = 0; r < 16; ++r) mx[r] = fmaxf(st[0][r], st[1][r]);
            #pragma unroll
            for (int s2 = 8; s2 > 0; s2 >>= 1)
                #pragma unroll
                for (int r = 0; r < s2; ++r) mx[r] = fmaxf(mx[r], mx[r + s2]);
            float tmax = fmaxf(mx[0], __shfl_xor(mx[0], 32));

            if (__any(tmax > m + 8.f)) {
                float mn = fmaxf(m, tmax);
                float al = EXP2(m - mn);
                m = mn;
                lsum *= al;
                #pragma unroll
                for (int dt = 0; dt < 2; ++dt)
                    #pragma unroll
                    for (int r = 0; r < 16; ++r) ot[dt][r] *= al;
            }

            float psa[4] = {0.f, 0.f, 0.f, 0.f};
            #pragma unroll
            for (int nt = 0; nt < 2; ++nt)
                #pragma unroll
                for (int r = 0; r < 16; ++r) {
                    float pv = EXP2(st[nt][r] - m);
                    st[nt][r] = pv;
                    psa[r & 3] += pv;
                }
            lsum += (psa[0] + psa[1]) + (psa[2] + psa[3]);

            #pragma unroll
            for (int nt = 0; nt < 2; ++nt) {
                unsigned a0 = cvt_pk_bf16(st[nt][0],  st[nt][1]);
                unsigned b0 = cvt_pk_bf16(st[nt][4],  st[nt][5]);
                unsigned a1 = cvt_pk_bf16(st[nt][2],  st[nt][3]);
                unsigned b1 = cvt_pk_bf16(st[nt][6],  st[nt][7]);
                int2v r0 = __builtin_amdgcn_permlane32_swap((int)a0, (int)b0, false, false);
                int2v r1 = __builtin_amdgcn_permlane32_swap((int)a1, (int)b1, false, false);
                union { unsigned u[4]; bf16x8 v; } pf0, pf1;
                pf0.u[0] = r0.x; pf0.u[1] = r1.x; pf0.u[2] = r0.y; pf0.u[3] = r1.y;
                unsigned c0 = cvt_pk_bf16(st[nt][8],  st[nt][9]);
                unsigned d0 = cvt_pk_bf16(st[nt][12], st[nt][13]);
                unsigned c1 = cvt_pk_bf16(st[nt][10], st[nt][11]);
                unsigned d1 = cvt_pk_bf16(st[nt][14], st[nt][15]);
                int2v r2 = __builtin_amdgcn_permlane32_swap((int)c0, (int)d0, false, false);
                int2v r3 = __builtin_amdgcn_permlane32_swap((int)c1, (int)d1, false, false);
                pf1.u[0] = r2.x; pf1.u[1] = r3.x; pf1.u[2] = r2.y; pf1.u[3] = r3.y;

                __builtin_amdgcn_s_setprio(1);
                #pragma unroll
                for (int dt = 0; dt < 2; ++dt) {
                    int d = dt * 32 + l31;
                    int v0off = (nt * 64 + h * 16) ^ ((d & 7) << 4);
                    bf16x8 vf0 = *(const bf16x8*)(&Vs[cur][((d << 7) + v0off) >> 1]);
                    ot[dt] = __builtin_amdgcn_mfma_f32_32x32x16_bf16(vf0, pf0.v, ot[dt], 0, 0, 0);
                }
                #pragma unroll
                for (int dt = 0; dt < 2; ++dt) {
                    int d = dt * 32 + l31;
                    int v1off = (nt * 64 + 32 + h * 16) ^ ((d & 7) << 4);
                    bf16x8 vf1 = *(const bf16x8*)(&Vs[cur][((d << 7) + v1off) >> 1]);
                    ot[dt] = __builtin_amdgcn_mfma_f32_32x32x16_bf16(vf1, pf1.v, ot[dt], 0, 0, 0);
                }
                __builtin_amdgcn_s_setprio(0);
            }
        }

        SBAR();
        if (kb + 2 < kb1) stage(kb + 2, cur);
    }

    // ---- epilogue ----
    float lf = lsum + __shfl_xor(lsum, 32);
    unsigned short* dst;
    size_t base;
    if (npart == 1 || p == 0) {
        dst = Y;  base = ((size_t)bb * Tc + q) * Cc + hh * 64;
    } else if (p == 1) {
        dst = P1; base = ((size_t)(bb * 1536 + (q - 512))) * Cc + hh * 64;
    } else {
        dst = P2; base = ((size_t)(bb * 768 + (q - 1280))) * Cc + hh * 64;
    }
    float inv = (npart == 1) ? 1.f / lf : 1.f;
    #pragma unroll
    for (int dt = 0; dt < 2; ++dt)
        #pragma unroll
        for (int rg = 0; rg < 4; ++rg) {
            int d0 = dt * 32 + rg * 8 + 4 * h;
            ushort4 s4;
            s4.x = f2bf(ot[dt][rg * 4 + 0] * inv);
            s4.y = f2bf(ot[dt][rg * 4 + 1] * inv);
            s4.z = f2bf(ot[dt][rg * 4 + 2] * inv);
            s4.w = f2bf(ot[dt][rg * 4 + 3] * inv);
            *(ushort4*)(dst + base + d0) = s4;
        }
    if (npart > 1 && h == 0) {
        int mi = p * 49152 + bh * 1536 + (q - 512);
        mlf[mi]          = m;
        mlf[147456 + mi] = lf;
    }
}

// ---------------------------------------------------------------------------
__global__ __launch_bounds__(256)
void attn_combine(unsigned short* __restrict__ Y,
                  const unsigned short* __restrict__ P1,
                  const unsigned short* __restrict__ P2,
                  const float* __restrict__ mlf) {
    int tid = blockIdx.x * 256 + threadIdx.x;    // 0 .. 393215
    int rowIdx = tid >> 7;                        // bb*1536 + (q-512)
    int col8 = (tid & 127) * 8;
    int bb = rowIdx / 1536, qoff = rowIdx % 1536;
    int q = 512 + qoff;
    int hh = col8 >> 6;
    int mi = (bb * 16 + hh) * 1536 + qoff;
    bool three = q >= 1280;

    float m0 = mlf[mi],          l0 = mlf[147456 + mi];
    float m1 = mlf[49152 + mi],  l1 = mlf[196608 + mi];
    float m2 = three ? mlf[98304 + mi]  : -INFINITY;
    float l2 = three ? mlf[245760 + mi] : 0.f;

    float M = fmaxf(fmaxf(m0, m1), m2);
    float a0 = exp2f(m0 - M), a1 = exp2f(m1 - M);
    float a2 = three ? exp2f(m2 - M) : 0.f;
    float inv = 1.f / (l0 * a0 + l1 * a1 + l2 * a2);

    size_t offY = ((size_t)(bb * Tc + q)) * Cc + col8;
    size_t off1 = ((size_t)rowIdx) * Cc + col8;
    union { unsigned short u[8]; bf16x8 v; } y0, y1, y2, r;
    y0.v = *(const bf16x8*)(Y + offY);
    y1.v = *(const bf16x8*)(P1 + off1);
    if (three) {
        size_t off2 = ((size_t)(bb * 768 + (q - 1280))) * Cc + col8;
        y2.v = *(const bf16x8*)(P2 + off2);
    }
    #pragma unroll
    for (int j = 0; j < 8; ++j) {
        float acc = bf2f(y0.u[j]) * a0 + bf2f(y1.u[j]) * a1;
        if (three) acc += bf2f(y2.u[j]) * a2;
        r.u[j] = f2bf(acc * inv);
    }
    *(bf16x8*)(Y + offY) = r.v;
}

// ---------------------------------------------------------------------------
extern "C" void kernel_launch(void* const* d_in, const int* in_sizes, int n_in,
                              void* d_out, int out_size, void* d_ws, size_t ws_size,
                              hipStream_t stream) {
    const float* x  = (const float*)d_in[0];
    const float* Wq = (const float*)d_in[1];
    const float* Wk = (const float*)d_in[2];
    const float* Wv = (const float*)d_in[3];
    const float* Wo = (const float*)d_in[4];

    unsigned short* ws = (unsigned short*)d_ws;
    const size_t nX = (size_t)Mc * Cc;   // 4194304
    const size_t nW = (size_t)Cc * Cc;   // 1048576
    size_t off = 0;
    unsigned short* xb  = ws + off; off += nX;   // dead after gemm_qkv -> P1
    unsigned short* Wqb = ws + off; off += nW;   // dead -> P2 (with Wkb)
    unsigned short* Wkb = ws + off; off += nW;
    unsigned short* Wvb = ws + off; off += nW;   // dead -> mlf
    unsigned short* Wob = ws + off; off += nW;   // LIVE until gemm_out
    unsigned short* Qw  = ws + off; off += nX;
    unsigned short* Kw  = ws + off; off += nX;
    unsigned short* Vtw = ws + off; off += nX;
    unsigned short* Yb  = ws + off; off += nX;

    dim3 blk(256);
    cast_all<<<dim3(4096), blk, 0, stream>>>(x, Wq, Wk, Wv, Wo, xb, Wqb, Wkb, Wvb, Wob);

    gemm_qkv<<<dim3(Mc / 128, 24), blk, 0, stream>>>(xb, Wqb, Wkb, Wvb, Qw, Kw, Vtw);

    unsigned short* P1 = xb;
    unsigned short* P2 = Wqb;            // spans Wqb+Wkb
    float* mlf = (float*)Wvb;
    attn_mfma<<<dim3(Bc * Hc, 34), blk, 0, stream>>>(Qw, Kw, Vtw, Yb, P1, P2, mlf);
    attn_combine<<<dim3(1536), blk, 0, stream>>>(Yb, P1, P2, mlf);

    gemm_out<<<dim3(Mc / 64, Cc / 64), blk, 0, stream>>>(Yb, Wob, (float*)d_out);
}

// Round 15
// 113.071 us; speedup vs baseline: 1.2328x; 1.0553x over previous
//
#include <hip/hip_runtime.h>
#include <math.h>

typedef short bf16x8 __attribute__((ext_vector_type(8)));
typedef float f32x4 __attribute__((ext_vector_type(4)));
typedef float f32x16 __attribute__((ext_vector_type(16)));
typedef int int2v __attribute__((ext_vector_type(2)));

constexpr int Bc = 2, Tc = 2048, Cc = 1024, Hc = 16, Dc = 64;
constexpr int Mc = Bc * Tc;  // 4096

#if __has_builtin(__builtin_amdgcn_exp2f)
#define EXP2(x) __builtin_amdgcn_exp2f(x)
#else
#define EXP2(x) exp2f(x)
#endif

#define SBAR() do { asm volatile("" ::: "memory"); \
                    __builtin_amdgcn_s_barrier();   \
                    asm volatile("" ::: "memory"); } while (0)

__device__ __forceinline__ unsigned short f2bf(float f) {
    union { float f; unsigned u; } v; v.f = f;
    unsigned r = v.u + 0x7fffu + ((v.u >> 16) & 1u);  // RNE
    return (unsigned short)(r >> 16);
}

__device__ __forceinline__ float bf2f(unsigned short u) {
    union { unsigned u; float f; } v; v.u = (unsigned)u << 16; return v.f;
}

__device__ __forceinline__ unsigned cvt_pk_bf16(float lo, float hi) {
    unsigned r;
    asm("v_cvt_pk_bf16_f32 %0, %1, %2" : "=v"(r) : "v"(lo), "v"(hi));
    return r;
}

__device__ __forceinline__ void gload16(const void* g, void* l) {
    __builtin_amdgcn_global_load_lds(
        (const __attribute__((address_space(1))) void*)g,
        (__attribute__((address_space(3))) void*)l, 16, 0, 0);
}

// ---------------------------------------------------------------------------
// One fused cast launch: blocks 0..2047 cast x; blocks 2048..4095 cast the
// 4 weights (512 blocks each).
// ---------------------------------------------------------------------------
__global__ __launch_bounds__(256)
void cast_all(const float* __restrict__ x,
              const float* __restrict__ wq, const float* __restrict__ wk,
              const float* __restrict__ wv, const float* __restrict__ wo,
              unsigned short* __restrict__ xo,
              unsigned short* __restrict__ oq, unsigned short* __restrict__ ok,
              unsigned short* __restrict__ ov, unsigned short* __restrict__ oo) {
    int bid = blockIdx.x;
    const float* src;
    unsigned short* dst;
    int i;
    if (bid < 2048) {
        src = x; dst = xo; i = bid * 256 + threadIdx.x;
    } else {
        int wsel = (bid - 2048) >> 9;
        src = wsel == 0 ? wq : wsel == 1 ? wk : wsel == 2 ? wv : wo;
        dst = wsel == 0 ? oq : wsel == 1 ? ok : wsel == 2 ? ov : oo;
        i = ((bid - 2048) & 511) * 256 + threadIdx.x;
    }
    const float4* p = (const float4*)src;
    float4 a = p[i * 2], b = p[i * 2 + 1];
    union { unsigned short u[8]; bf16x8 v; } r;
    r.u[0] = f2bf(a.x); r.u[1] = f2bf(a.y); r.u[2] = f2bf(a.z); r.u[3] = f2bf(a.w);
    r.u[4] = f2bf(b.x); r.u[5] = f2bf(b.y); r.u[6] = f2bf(b.z); r.u[7] = f2bf(b.w);
    *(bf16x8*)(dst + i * 8) = r.v;
}

// ---------------------------------------------------------------------------
// Fused QKV GEMM (NT) -- measured-best config (R4/R11, byte-exact): 128x128
// tile, BK=32, 4 waves, single-buffer 2-barrier loop, 768 blocks, scalar
// epilogue (VGPR 76 -> ~29% occupancy; branchy/vectorized epilogues raise
// VGPR to 104 and cost more than they save -- R14 lesson).
// blockIdx.y: 0..7 -> Q (scaled 0.125*log2e), 8..15 -> K, 16..23 -> V^T.
// ---------------------------------------------------------------------------
__global__ __launch_bounds__(256)
void gemm_qkv(const unsigned short* __restrict__ A,
              const unsigned short* __restrict__ Wq,
              const unsigned short* __restrict__ Wk,
              const unsigned short* __restrict__ Wv,
              unsigned short* __restrict__ Qo,
              unsigned short* __restrict__ Ko,
              unsigned short* __restrict__ Vo) {
    __shared__ unsigned short As[128 * 32];
    __shared__ unsigned short Bs[128 * 32];
    const int t = threadIdx.x;
    const int lane = t & 63, l15 = lane & 15, l4 = lane >> 4;
    const int w = t >> 6, wr = w >> 1, wc = w & 1;
    const int seg = blockIdx.y >> 3;              // 0=Q 1=K 2=V
    const unsigned short* W = seg == 0 ? Wq : seg == 1 ? Wk : Wv;
    const int m0 = blockIdx.x * 128, n0 = (blockIdx.y & 7) * 128;

    f32x4 acc[4][4] = {};

    for (int k0 = 0; k0 < Cc; k0 += 32) {
        __syncthreads();
        #pragma unroll
        for (int it = 0; it < 2; ++it) {
            int c = t + it * 256;
            int row = c >> 2, ko = (c & 3) << 3;
            gload16(A + (size_t)(m0 + row) * Cc + k0 + ko, As + c * 8);
            gload16(W + (size_t)(n0 + row) * Cc + k0 + ko, Bs + c * 8);
        }
        __syncthreads();
        bf16x8 af[4], bfr[4];
        #pragma unroll
        for (int i = 0; i < 4; ++i)
            af[i] = *(const bf16x8*)(As + ((wr * 64 + i * 16 + l15) * 32 + l4 * 8));
        #pragma unroll
        for (int j = 0; j < 4; ++j)
            bfr[j] = *(const bf16x8*)(Bs + ((wc * 64 + j * 16 + l15) * 32 + l4 * 8));
        #pragma unroll
        for (int i = 0; i < 4; ++i)
            #pragma unroll
            for (int j = 0; j < 4; ++j)
                acc[i][j] = __builtin_amdgcn_mfma_f32_16x16x32_bf16(af[i], bfr[j], acc[i][j], 0, 0, 0);
    }

    const float qscale = 0.18033688011112042f;  // 0.125 * log2(e)
    const int r0 = wr * 64 + (l4 << 2);
    const int c0 = wc * 64 + l15;
    #pragma unroll
    for (int i = 0; i < 4; ++i)
        #pragma unroll
        for (int j = 0; j < 4; ++j)
            #pragma unroll
            for (int r = 0; r < 4; ++r) {
                int row = m0 + r0 + i * 16 + r;
                int col = n0 + c0 + j * 16;
                float v = acc[i][j][r];
                int bb = row >> 11, tt = row & (Tc - 1);
                int hh = col >> 6, dd = col & 63;
                if (seg == 0)
                    Qo[((((size_t)bb * Hc + hh) * Tc + tt) << 6) + dd] = f2bf(v * qscale);
                else if (seg == 1)
                    Ko[((((size_t)bb * Hc + hh) * Tc + tt) << 6) + dd] = f2bf(v);
                else
                    Vo[(((size_t)bb * Hc + hh) * Dc + dd) * Tc + tt] = f2bf(v);
            }
}

// ---------------------------------------------------------------------------
// Out-projection GEMM (NT): 64x64 tile, 1024 blocks (4/CU), fp32 out [M,C].
// ---------------------------------------------------------------------------
__global__ __launch_bounds__(256)
void gemm_out(const unsigned short* __restrict__ A,
              const unsigned short* __restrict__ W,
              float* __restrict__ outp) {
    __shared__ unsigned short As[64 * 32];
    __shared__ unsigned short Bs[64 * 32];
    const int t = threadIdx.x;
    const int lane = t & 63, l15 = lane & 15, l4 = lane >> 4;
    const int w = t >> 6, wr = w >> 1, wc = w & 1;
    const int m0 = blockIdx.x * 64, n0 = blockIdx.y * 64;

    f32x4 acc[2][2] = {};

    for (int k0 = 0; k0 < Cc; k0 += 32) {
        __syncthreads();
        {
            int row = t >> 2, ko = (t & 3) << 3;
            gload16(A + (size_t)(m0 + row) * Cc + k0 + ko, As + t * 8);
            gload16(W + (size_t)(n0 + row) * Cc + k0 + ko, Bs + t * 8);
        }
        __syncthreads();
        bf16x8 af[2], bfr[2];
        #pragma unroll
        for (int i = 0; i < 2; ++i)
            af[i] = *(const bf16x8*)(As + ((wr * 32 + i * 16 + l15) * 32 + l4 * 8));
        #pragma unroll
        for (int j = 0; j < 2; ++j)
            bfr[j] = *(const bf16x8*)(Bs + ((wc * 32 + j * 16 + l15) * 32 + l4 * 8));
        #pragma unroll
        for (int i = 0; i < 2; ++i)
            #pragma unroll
            for (int j = 0; j < 2; ++j)
                acc[i][j] = __builtin_amdgcn_mfma_f32_16x16x32_bf16(af[i], bfr[j], acc[i][j], 0, 0, 0);
    }

    const int r0 = wr * 32 + (l4 << 2);
    const int c0 = wc * 32 + l15;
    #pragma unroll
    for (int i = 0; i < 2; ++i)
        #pragma unroll
        for (int j = 0; j < 2; ++j)
            #pragma unroll
            for (int r = 0; r < 4; ++r)
                outp[(size_t)(m0 + r0 + i * 16 + r) * Cc + n0 + c0 + j * 16] = acc[i][j][r];
}

// ---------------------------------------------------------------------------
// MFMA causal flash attention. 4 waves x 32 q-rows = 128 rows/block sharing
// one 32 KB K+V dbuf. Counted vmcnt(4). Split-K on 128-row chunks:
// c<4 unsplit, c=4..9 2-way, c>=10 3-way. 34 LPT jobs/bh, grid 32x34.
// ---------------------------------------------------------------------------
__device__ __constant__ unsigned char JOBS[34] = {
    61, 62,                                  // 11 tiles
    60, 56, 57, 58, 54, 36, 37,              // 10
    52, 53, 49, 50, 32, 33,                  // 9
    48, 44, 45, 46, 42, 28, 29, 12,          // 8
    40, 41, 24, 25,                          // 7
    20, 21, 8,                               // 6
    16, 17,                                  // 5
    4, 0                                     // 4, 2
};

__global__ __launch_bounds__(256)
void attn_mfma(const unsigned short* __restrict__ Q,
               const unsigned short* __restrict__ K,
               const unsigned short* __restrict__ Vt,
               unsigned short* __restrict__ Y,
               unsigned short* __restrict__ P1,   // p=1 partials, q in [512,2048)
               unsigned short* __restrict__ P2,   // p=2 partials, q in [1280,2048)
               float* __restrict__ mlf) {         // m[3][32][1536], l[3][32][1536]
    __shared__ unsigned short Ks[2][64 * 64];  // [buf][key][d]   (swizzled)
    __shared__ unsigned short Vs[2][64 * 64];  // [buf][d][key]   (swizzled)

    const int t = threadIdx.x, lane = t & 63, w = t >> 6;   // w = 0..3
    const int l31 = lane & 31, h = lane >> 5;
    const int bh = blockIdx.x;
    const int bb = bh >> 4, hh = bh & 15;

    const unsigned char job = JOBS[blockIdx.y];
    const int c = job >> 2, p = job & 3;
    const int n = 2 * c + 2;                       // tiles in chunk
    const int npart = c < 4 ? 1 : (c < 10 ? 2 : 3);
    const int kb0 = p * n / npart;
    const int kb1 = (p + 1) * n / npart;

    const int qbase = c * 128 + w * 32;
    const int q = qbase + l31;

    const unsigned short* Qp = Q + (size_t)bh * Tc * Dc;
    const unsigned short* Kp = K + (size_t)bh * Tc * Dc;
    const unsigned short* Vp = Vt + (size_t)bh * Dc * Tc;

    bf16x8 qf[4];
    #pragma unroll
    for (int kc = 0; kc < 4; ++kc)
        qf[kc] = *(const bf16x8*)(Qp + (size_t)q * 64 + kc * 16 + h * 8);

    f32x16 ot[2] = {};          // O^T: rows d=dt*32+(r&3)+8*(r>>2)+4h, col q
    float m = -INFINITY, lsum = 0.f;

    auto stage = [&](int kb, int buf) {
        #pragma unroll
        for (int it = 0; it < 2; ++it) {
            int idx = t + it * 256;           // 0..511
            int row = idx >> 3, slot = idx & 7;
            int ss = slot ^ (row & 7);        // pre-swizzled source
            gload16(Kp + (size_t)(kb * 64 + row) * 64 + ss * 8, &Ks[buf][idx * 8]);
            gload16(Vp + (size_t)row * Tc + kb * 64 + ss * 8, &Vs[buf][idx * 8]);
        }
    };

    stage(kb0, 0);
    if (kb0 + 1 < kb1) stage(kb0 + 1, 1);

    for (int kb = kb0; kb < kb1; ++kb) {
        const int cur = (kb - kb0) & 1;
        if (kb + 1 < kb1) asm volatile("s_waitcnt vmcnt(4)" ::: "memory");
        else              asm volatile("s_waitcnt vmcnt(0)" ::: "memory");
        SBAR();

        const bool active = (kb * 64 <= qbase + 31);
        if (active) {
            // ---- S^T = K @ Q^T  (log2 domain; 2 key-tiles of 32) ----
            f32x16 st[2] = {};
            __builtin_amdgcn_s_setprio(1);
            #pragma unroll
            for (int nt = 0; nt < 2; ++nt) {
                int key = nt * 32 + l31;
                #pragma unroll
                for (int kc = 0; kc < 4; ++kc) {
                    int boff = (kc * 32 + h * 16) ^ ((key & 7) << 4);
                    bf16x8 kf = *(const bf16x8*)(&Ks[cur][((key << 7) + boff) >> 1]);
                    st[nt] = __builtin_amdgcn_mfma_f32_32x32x16_bf16(kf, qf[kc], st[nt], 0, 0, 0);
                }
            }
            __builtin_amdgcn_s_setprio(0);

            if (kb * 64 + 63 > qbase) {  // causal mask (diagonal region)
                #pragma unroll
                for (int nt = 0; nt < 2; ++nt)
                    #pragma unroll
                    for (int r = 0; r < 16; ++r) {
                        int key = kb * 64 + nt * 32 + (r & 3) + 8 * (r >> 2) + 4 * h;
                        if (key > q) st[nt][r] = -1e30f;
                    }
            }

            float mx[16];
            #pragma unroll
            for (int r = 0; r < 16; ++r) mx[r] = fmaxf(st[0][r], st[1][r]);
            #pragma unroll
            for (int s2 = 8; s2 > 0; s2 >>= 1)
                #pragma unroll
                for (int r = 0; r < s2; ++r) mx[r] = fmaxf(mx[r], mx[r + s2]);
            float tmax = fmaxf(mx[0], __shfl_xor(mx[0], 32));

            if (__any(tmax > m + 8.f)) {
                float mn = fmaxf(m, tmax);
                float al = EXP2(m - mn);
                m = mn;
                lsum *= al;
                #pragma unroll
                for (int dt = 0; dt < 2; ++dt)
                    #pragma unroll
                    for (int r = 0; r < 16; ++r) ot[dt][r] *= al;
            }

            float psa[4] = {0.f, 0.f, 0.f, 0.f};
            #pragma unroll
            for (int nt = 0; nt < 2; ++nt)
                #pragma unroll
                for (int r = 0; r < 16; ++r) {
                    float pv = EXP2(st[nt][r] - m);
                    st[nt][r] = pv;
                    psa[r & 3] += pv;
                }
            lsum += (psa[0] + psa[1]) + (psa[2] + psa[3]);

            #pragma unroll
            for (int nt = 0; nt < 2; ++nt) {
                unsigned a0 = cvt_pk_bf16(st[nt][0],  st[nt][1]);
                unsigned b0 = cvt_pk_bf16(st[nt][4],  st[nt][5]);
                unsigned a1 = cvt_pk_bf16(st[nt][2],  st[nt][3]);
                unsigned b1 = cvt_pk_bf16(st[nt][6],  st[nt][7]);
                int2v r0 = __builtin_amdgcn_permlane32_swap((int)a0, (int)b0, false, false);
                int2v r1 = __builtin_amdgcn_permlane32_swap((int)a1, (int)b1, false, false);
                union { unsigned u[4]; bf16x8 v; } pf0, pf1;
                pf0.u[0] = r0.x; pf0.u[1] = r1.x; pf0.u[2] = r0.y; pf0.u[3] = r1.y;
                unsigned c0 = cvt_pk_bf16(st[nt][8],  st[nt][9]);
                unsigned d0 = cvt_pk_bf16(st[nt][12], st[nt][13]);
                unsigned c1 = cvt_pk_bf16(st[nt][10], st[nt][11]);
                unsigned d1 = cvt_pk_bf16(st[nt][14], st[nt][15]);
                int2v r2 = __builtin_amdgcn_permlane32_swap((int)c0, (int)d0, false, false);
                int2v r3 = __builtin_amdgcn_permlane32_swap((int)c1, (int)d1, false, false);
                pf1.u[0] = r2.x; pf1.u[1] = r3.x; pf1.u[2] = r2.y; pf1.u[3] = r3.y;

                __builtin_amdgcn_s_setprio(1);
                #pragma unroll
                for (int dt = 0; dt < 2; ++dt) {
                    int d = dt * 32 + l31;
                    int v0off = (nt * 64 + h * 16) ^ ((d & 7) << 4);
                    bf16x8 vf0 = *(const bf16x8*)(&Vs[cur][((d << 7) + v0off) >> 1]);
                    ot[dt] = __builtin_amdgcn_mfma_f32_32x32x16_bf16(vf0, pf0.v, ot[dt], 0, 0, 0);
                }
                #pragma unroll
                for (int dt = 0; dt < 2; ++dt) {
                    int d = dt * 32 + l31;
                    int v1off = (nt * 64 + 32 + h * 16) ^ ((d & 7) << 4);
                    bf16x8 vf1 = *(const bf16x8*)(&Vs[cur][((d << 7) + v1off) >> 1]);
                    ot[dt] = __builtin_amdgcn_mfma_f32_32x32x16_bf16(vf1, pf1.v, ot[dt], 0, 0, 0);
                }
                __builtin_amdgcn_s_setprio(0);
            }
        }

        SBAR();
        if (kb + 2 < kb1) stage(kb + 2, cur);
    }

    // ---- epilogue ----
    float lf = lsum + __shfl_xor(lsum, 32);
    unsigned short* dst;
    size_t base;
    if (npart == 1 || p == 0) {
        dst = Y;  base = ((size_t)bb * Tc + q) * Cc + hh * 64;
    } else if (p == 1) {
        dst = P1; base = ((size_t)(bb * 1536 + (q - 512))) * Cc + hh * 64;
    } else {
        dst = P2; base = ((size_t)(bb * 768 + (q - 1280))) * Cc + hh * 64;
    }
    float inv = (npart == 1) ? 1.f / lf : 1.f;
    #pragma unroll
    for (int dt = 0; dt < 2; ++dt)
        #pragma unroll
        for (int rg = 0; rg < 4; ++rg) {
            int d0 = dt * 32 + rg * 8 + 4 * h;
            ushort4 s4;
            s4.x = f2bf(ot[dt][rg * 4 + 0] * inv);
            s4.y = f2bf(ot[dt][rg * 4 + 1] * inv);
            s4.z = f2bf(ot[dt][rg * 4 + 2] * inv);
            s4.w = f2bf(ot[dt][rg * 4 + 3] * inv);
            *(ushort4*)(dst + base + d0) = s4;
        }
    if (npart > 1 && h == 0) {
        int mi = p * 49152 + bh * 1536 + (q - 512);
        mlf[mi]          = m;
        mlf[147456 + mi] = lf;
    }
}

// ---------------------------------------------------------------------------
__global__ __launch_bounds__(256)
void attn_combine(unsigned short* __restrict__ Y,
                  const unsigned short* __restrict__ P1,
                  const unsigned short* __restrict__ P2,
                  const float* __restrict__ mlf) {
    int tid = blockIdx.x * 256 + threadIdx.x;    // 0 .. 393215
    int rowIdx = tid >> 7;                        // bb*1536 + (q-512)
    int col8 = (tid & 127) * 8;
    int bb = rowIdx / 1536, qoff = rowIdx % 1536;
    int q = 512 + qoff;
    int hh = col8 >> 6;
    int mi = (bb * 16 + hh) * 1536 + qoff;
    bool three = q >= 1280;

    float m0 = mlf[mi],          l0 = mlf[147456 + mi];
    float m1 = mlf[49152 + mi],  l1 = mlf[196608 + mi];
    float m2 = three ? mlf[98304 + mi]  : -INFINITY;
    float l2 = three ? mlf[245760 + mi] : 0.f;

    float M = fmaxf(fmaxf(m0, m1), m2);
    float a0 = exp2f(m0 - M), a1 = exp2f(m1 - M);
    float a2 = three ? exp2f(m2 - M) : 0.f;
    float inv = 1.f / (l0 * a0 + l1 * a1 + l2 * a2);

    size_t offY = ((size_t)(bb * Tc + q)) * Cc + col8;
    size_t off1 = ((size_t)rowIdx) * Cc + col8;
    union { unsigned short u[8]; bf16x8 v; } y0, y1, y2, r;
    y0.v = *(const bf16x8*)(Y + offY);
    y1.v = *(const bf16x8*)(P1 + off1);
    if (three) {
        size_t off2 = ((size_t)(bb * 768 + (q - 1280))) * Cc + col8;
        y2.v = *(const bf16x8*)(P2 + off2);
    }
    #pragma unroll
    for (int j = 0; j < 8; ++j) {
        float acc = bf2f(y0.u[j]) * a0 + bf2f(y1.u[j]) * a1;
        if (three) acc += bf2f(y2.u[j]) * a2;
        r.u[j] = f2bf(acc * inv);
    }
    *(bf16x8*)(Y + offY) = r.v;
}

// ---------------------------------------------------------------------------
extern "C" void kernel_launch(void* const* d_in, const int* in_sizes, int n_in,
                              void* d_out, int out_size, void* d_ws, size_t ws_size,
                              hipStream_t stream) {
    const float* x  = (const float*)d_in[0];
    const float* Wq = (const float*)d_in[1];
    const float* Wk = (const float*)d_in[2];
    const float* Wv = (const float*)d_in[3];
    const float* Wo = (const float*)d_in[4];

    unsigned short* ws = (unsigned short*)d_ws;
    const size_t nX = (size_t)Mc * Cc;   // 4194304
    const size_t nW = (size_t)Cc * Cc;   // 1048576
    size_t off = 0;
    unsigned short* xb  = ws + off; off += nX;   // dead after gemm_qkv -> P1
    unsigned short* Wqb = ws + off; off += nW;   // dead -> P2 (with Wkb)
    unsigned short* Wkb = ws + off; off += nW;
    unsigned short* Wvb = ws + off; off += nW;   // dead -> mlf
    unsigned short* Wob = ws + off; off += nW;   // LIVE until gemm_out
    unsigned short* Qw  = ws + off; off += nX;
    unsigned short* Kw  = ws + off; off += nX;
    unsigned short* Vtw = ws + off; off += nX;
    unsigned short* Yb  = ws + off; off += nX;

    dim3 blk(256);
    cast_all<<<dim3(4096), blk, 0, stream>>>(x, Wq, Wk, Wv, Wo, xb, Wqb, Wkb, Wvb, Wob);

    gemm_qkv<<<dim3(Mc / 128, 24), blk, 0, stream>>>(xb, Wqb, Wkb, Wvb, Qw, Kw, Vtw);

    unsigned short* P1 = xb;
    unsigned short* P2 = Wqb;            // spans Wqb+Wkb
    float* mlf = (float*)Wvb;
    attn_mfma<<<dim3(Bc * Hc, 34), blk, 0, stream>>>(Qw, Kw, Vtw, Yb, P1, P2, mlf);
    attn_combine<<<dim3(1536), blk, 0, stream>>>(Yb, P1, P2, mlf);

    gemm_out<<<dim3(Mc / 64, Cc / 64), blk, 0, stream>>>(Yb, Wob, (float*)d_out);
}